// Round 3
// baseline (246.425 us; speedup 1.0000x reference)
//
#include <hip/hip_runtime.h>
#include <hip/hip_bf16.h>
#include <math.h>

// Fully-fused TCN, R12: weights global->VGPR (bypass LDS).
// R11 budget: LDS pipe ~45% (largest), 40% of reads were weight fragments.
// Each wave's weight fragment is a private static 16B slice -> load straight
// from the (unswizzled) weight bank with global_load_dwordx4, double-buffered
// in registers at tap granularity (wA/wB), prefetch distance = 1 tap.
// Weights are L2-resident (624 KB, HBM idle at 5%). Removes stage_async, the
// 64KB weight LDS (x1 -> freed LDS region), 40% of LDS reads, and drops
// barriers 22 -> 12. 16 waves (4/SIMD) kept; VGPR budget ~115 (<=128 req).
// LDS = 3 x (192x128) bf16 regions (RA, RB, X1) = 147456 B (144 KiB).

typedef __attribute__((ext_vector_type(8))) short short8;
typedef __attribute__((ext_vector_type(4))) short short4v;
typedef __attribute__((ext_vector_type(4))) float floatx4;

#define S_LEN 4096
#define ACT_STRIDE 128             // no pad; swizzle handles banks
#define ROWS 192                   // 64 halo + 128 outputs
#define AREG (ROWS * ACT_STRIDE)   // 24576 shorts per activation region
#define LDS_BYTES (3 * AREG * 2)   // 147456 B

// 16B-granular XOR swizzle for activations (col in shorts)
#define SW(row, col) ((col) ^ (((row) & 7) << 3))

// weight bank offsets (shorts) — each tap contiguous [co][ci] row-major
#define OFF_DS     0
#define OFF_L0C1_0 8192
#define OFF_L0C1_1 16384
#define OFF_L0C2_0 24576
#define OFF_L0C2_1 40960
#define OFF_C1B    57344      // + lvl*32768 ; tap1 at +16384
#define OFF_C2B    188416     // + lvl*32768 ; tap1 at +16384

__device__ __forceinline__ float elu_f(float v) {
    return v > 0.0f ? v : (__expf(v) - 1.0f);
}
__device__ __forceinline__ short f2bs(float v) {
    __hip_bfloat16 h = __float2bfloat16(v);
    return *reinterpret_cast<short*>(&h);
}
__device__ __forceinline__ float bs2f(short s) {
    __hip_bfloat16 h = *reinterpret_cast<__hip_bfloat16*>(&s);
    return __bfloat162float(h);
}
__device__ __forceinline__ short4v pack4(const floatx4 v) {
    __hip_bfloat162 p0 = __float22bfloat162_rn(make_float2(v[0], v[1]));
    __hip_bfloat162 p1 = __float22bfloat162_rn(make_float2(v[2], v[3]));
    short4v r;
    r[0] = ((const short*)&p0)[0]; r[1] = ((const short*)&p0)[1];
    r[2] = ((const short*)&p1)[0]; r[3] = ((const short*)&p1)[1];
    return r;
}

// ---------------------------------------------------------------------------
// Load one tap's weight fragments for this wave straight into registers.
// Lane (l16, quad) of co-group cobase holds W[cobase+mt*16+l16][kc*32+quad*8..+7].
// ---------------------------------------------------------------------------
template<int KCH>
__device__ __forceinline__ void load_w(short8 (&w)[2][4],
                                       const short* __restrict__ wt,
                                       int cobase, int l16, int quad)
{
    const short* base = wt + (cobase + l16) * (KCH * 32) + quad * 8;
    #pragma unroll
    for (int mt = 0; mt < 2; ++mt)
        #pragma unroll
        for (int kc = 0; kc < KCH; ++kc)
            w[mt][kc] = *(const short8*)(base + mt * 16 * KCH * 32 + kc * 32);
}

// ---------------------------------------------------------------------------
// One tap's MFMAs: acc[mt][nt] += W[co][ci] * X[r - doff][ci].
// Weights from registers, activations ds_read_b128 from swizzled LDS.
// ---------------------------------------------------------------------------
template<int KCH>
__device__ __forceinline__ void conv_tap(
    const short* __restrict__ Lin, const short8 (&w)[2][4],
    const int doff, const int srow, const int l16, const int quad,
    floatx4 (&acc)[2][3])
{
    #pragma unroll
    for (int kc = 0; kc < KCH; ++kc) {
        const int col = kc * 32 + quad * 8;
        #pragma unroll
        for (int nt = 0; nt < 3; ++nt) {
            int r = srow + nt * 16 + l16 - doff;
            if (r < 0) r = 0;              // clamped rows never feed valid outputs
            const short8 bf = *(const short8*)(Lin + r * ACT_STRIDE + SW(r, col));
            #pragma unroll
            for (int mt = 0; mt < 2; ++mt)
                acc[mt][nt] = __builtin_amdgcn_mfma_f32_16x16x32_bf16(w[mt][kc], bf, acc[mt][nt], 0, 0, 0);
        }
    }
}

__device__ __forceinline__ void zero_acc(floatx4 (&acc)[2][3]) {
    #pragma unroll
    for (int mt = 0; mt < 2; ++mt)
        #pragma unroll
        for (int nt = 0; nt < 3; ++nt) acc[mt][nt] = {0.f, 0.f, 0.f, 0.f};
}

// ---------------------------------------------------------------------------
// Packed epilogue (swizzled addresses). MODE 0: elu(acc+b); 1: acc+b;
// 2: elu(elu(acc+b)+dst) in place (own-lane read+write).
// KEEP: also duplicate the packed result into x1dst (freed-LDS x1 buffer).
// ---------------------------------------------------------------------------
template<int MODE, bool KEEP>
__device__ __forceinline__ void store_tile(short* __restrict__ dst,
    const floatx4 (&acc)[2][3], const float* __restrict__ bias,
    int cobase, int srow, int l16, int quad, int zero_below,
    short* __restrict__ x1dst)
{
    #pragma unroll
    for (int mt = 0; mt < 2; ++mt) {
        const int co4 = cobase + mt * 16 + quad * 4;
        const floatx4 bb = *(const floatx4*)(bias + co4);
        #pragma unroll
        for (int nt = 0; nt < 3; ++nt) {
            const int sl = srow + nt * 16 + l16;
            const int off = sl * ACT_STRIDE + SW(sl, co4);
            short* p = dst + off;
            floatx4 y;
            #pragma unroll
            for (int rr = 0; rr < 4; ++rr) {
                float v = acc[mt][nt][rr] + bb[rr];
                if (MODE != 1) v = elu_f(v);
                y[rr] = v;
            }
            if (MODE == 2) {
                const short4v old = *(const short4v*)p;
                #pragma unroll
                for (int rr = 0; rr < 4; ++rr) y[rr] = elu_f(y[rr] + bs2f(old[rr]));
            }
            if (sl < zero_below) y = {0.f, 0.f, 0.f, 0.f};
            const short4v pk = pack4(y);
            *(short4v*)p = pk;
            if (KEEP) *(short4v*)(x1dst + off) = pk;
        }
    }
}

// ---------------------------------------------------------------------------
__global__ __launch_bounds__(1024, 4)
void tcn_fused(const float* __restrict__ x,     // fp32 [16,64,4096] channel-first
               const short* __restrict__ wq,
               const float* __restrict__ b1_0, const float* __restrict__ b2_0,
               const float* __restrict__ ds_b, const float* __restrict__ B1,
               const float* __restrict__ B2, float* __restrict__ out)
{
    extern __shared__ short L[];
    short* RA = L;                 // T buffer (also X staging)
    short* RB = L + AREG;          // D buffer (residual chain)
    short* X1 = L + 2 * AREG;      // level-0 output kept for final skip

    const int tid  = threadIdx.x;
    const int wave = tid >> 6, lane = tid & 63;
    const int l16  = lane & 15, quad = lane >> 4;
    const int cobase = (wave & 3) * 32;    // 4 co-groups of 32
    const int srow   = (wave >> 2) * 48;   // 4 row-groups of 48
    const int s0  = blockIdx.x * 128;
    const int s0g = s0 - 64;
    const int b   = blockIdx.y;
    const int zb  = (s0 == 0) ? 64 : 0;   // zero rows with global s < 0

    short8 wA[2][4], wB[2][4];
    floatx4 acc[2][3];

    // ---- prologue: issue ds-tap weight loads, then stage X into RA
    load_w<2>(wA, wq + OFF_DS, cobase, l16, quad);
    {
        const float* xp = x + (size_t)b * 64 * S_LEN;
        #pragma unroll
        for (int h = 0; h < 3; ++h) {
            const int r = lane + h * 64;
            const int s = s0g + r;
            short4v pk;
            #pragma unroll
            for (int c4 = 0; c4 < 4; ++c4) {
                const float v = (s >= 0) ? xp[(wave * 4 + c4) * S_LEN + s] : 0.f;
                pk[c4] = f2bs(v);
            }
            *(short4v*)(RA + r * ACT_STRIDE + SW(r, wave * 4)) = pk;
        }
    }
    __syncthreads();                               // B0: X visible

    // ---- ds (1x1, CIN=64): X(RA) -> D(RB)   [no barrier after: disjoint]
    load_w<2>(wB, wq + OFF_L0C1_0, cobase, l16, quad);
    zero_acc(acc);
    conv_tap<2>(RA, wA, 0, srow, l16, quad, acc);
    store_tile<1, false>(RB, acc, ds_b, cobase, srow, l16, quad, zb, nullptr);

    // ---- c1_0 (d=1, CIN=64): reads X(RA), writes T over RA (in place)
    load_w<2>(wA, wq + OFF_L0C1_1, cobase, l16, quad);
    zero_acc(acc);
    conv_tap<2>(RA, wB, 1, srow, l16, quad, acc);
    load_w<4>(wB, wq + OFF_L0C2_0, cobase, l16, quad);
    conv_tap<2>(RA, wA, 0, srow, l16, quad, acc);
    __syncthreads();                               // B1: all X reads done
    store_tile<0, false>(RA, acc, b1_0, cobase, srow, l16, quad, zb, nullptr);
    __syncthreads();                               // B2: T published

    // ---- c2_0 (d=1, CIN=128): reads T(RA), res RB -> RB in place; dup to X1
    load_w<4>(wA, wq + OFF_L0C2_1, cobase, l16, quad);
    zero_acc(acc);
    conv_tap<4>(RA, wB, 1, srow, l16, quad, acc);
    load_w<4>(wB, wq + OFF_C1B, cobase, l16, quad);
    conv_tap<4>(RA, wA, 0, srow, l16, quad, acc);
    store_tile<2, true>(RB, acc, b2_0, cobase, srow, l16, quad, zb, X1);
    __syncthreads();                               // B3: level-0 out published

    // ---- levels 1..3 (d = 2, 4, 8)
    #pragma unroll
    for (int lvl = 0; lvl < 3; ++lvl) {
        const int d = 2 << lvl;
        // c1 k0: RB -> acc              (uses wB, prefetch c1k1 -> wA)
        load_w<4>(wA, wq + OFF_C1B + lvl * 32768 + 16384, cobase, l16, quad);
        zero_acc(acc);
        conv_tap<4>(RB, wB, d, srow, l16, quad, acc);
        // c1 k1: store T -> RA          (uses wA, prefetch c2k0 -> wB)
        load_w<4>(wB, wq + OFF_C2B + lvl * 32768, cobase, l16, quad);
        conv_tap<4>(RB, wA, 0, srow, l16, quad, acc);
        store_tile<0, false>(RA, acc, B1 + lvl * 128, cobase, srow, l16, quad, zb, nullptr);
        __syncthreads();                           // T published
        // c2 k0: RA -> acc              (uses wB, prefetch c2k1 -> wA)
        load_w<4>(wA, wq + OFF_C2B + lvl * 32768 + 16384, cobase, l16, quad);
        zero_acc(acc);
        conv_tap<4>(RA, wB, d, srow, l16, quad, acc);
        // c2 k1: RB in place (res)      (uses wA, prefetch next c1k0 -> wB)
        load_w<4>(wB, wq + OFF_C1B + (lvl + 1) * 32768, cobase, l16, quad);
        conv_tap<4>(RA, wA, 0, srow, l16, quad, acc);
        store_tile<2, false>(RB, acc, B2 + lvl * 128, cobase, srow, l16, quad, zb, nullptr);
        __syncthreads();                           // level out published
    }

    // ---- level 4 (d=16)
    // c1 k0 (uses wB, prefetch c1k1 -> wA)
    load_w<4>(wA, wq + OFF_C1B + 3 * 32768 + 16384, cobase, l16, quad);
    zero_acc(acc);
    conv_tap<4>(RB, wB, 16, srow, l16, quad, acc);
    // c1 k1 -> RA (uses wA, prefetch c2k0 -> wB)
    load_w<4>(wB, wq + OFF_C2B + 3 * 32768, cobase, l16, quad);
    conv_tap<4>(RB, wA, 0, srow, l16, quad, acc);
    store_tile<0, false>(RA, acc, B1 + 384, cobase, srow, l16, quad, zb, nullptr);
    __syncthreads();                               // T published
    // c2 k0 (uses wB, prefetch c2k1 -> wA)
    load_w<4>(wA, wq + OFF_C2B + 3 * 32768 + 16384, cobase, l16, quad);
    zero_acc(acc);
    conv_tap<4>(RA, wB, 16, srow, l16, quad, acc);
    // c2 k1 (uses wA) -> final epilogue, rows 64..191 only
    conv_tap<4>(RA, wA, 0, srow, l16, quad, acc);
    {
        #pragma unroll
        for (int mt = 0; mt < 2; ++mt) {
            const int co4 = cobase + mt * 16 + quad * 4;
            const floatx4 bb = *(const floatx4*)(B2 + 384 + co4);
            #pragma unroll
            for (int nt = 0; nt < 3; ++nt) {
                if (srow + nt * 16 < 64) continue;     // halo rows: no output
                const int sl = srow + nt * 16 + l16;
                const int sg = s0g + sl;
                const int off = sl * ACT_STRIDE + SW(sl, co4);
                const short4v res = *(const short4v*)(RB + off);
                const short4v k   = *(const short4v*)(X1 + off);
                #pragma unroll
                for (int rr = 0; rr < 4; ++rr) {
                    float y = elu_f(acc[mt][nt][rr] + bb[rr]);
                    y = elu_f(y + bs2f(res[rr]));
                    y += bs2f(k[rr]);
                    out[((size_t)(b * 128 + co4 + rr)) * S_LEN + sg] = y;
                }
            }
        }
    }
}

// ---------------------------------------------------------------------------
// weights fp32 [co][ci][k] -> bf16 tap matrices [co][ci], PLAIN row-major
// (register path reads the logical layout directly; no swizzle needed).
// ---------------------------------------------------------------------------
__global__ __launch_bounds__(256)
void prep_w(const float* __restrict__ w1_0, const float* __restrict__ w2_0,
            const float* __restrict__ ds_w, const float* __restrict__ W1,
            const float* __restrict__ W2, short* __restrict__ wq)
{
    int idx = blockIdx.x * 256 + threadIdx.x;
    const int n_c1 = 128 * 64;
    const int n_c2 = 128 * 128;
    if (idx < n_c1) {
        wq[OFF_L0C1_0 + idx] = f2bs(w1_0[idx * 2]);
        wq[OFF_L0C1_1 + idx] = f2bs(w1_0[idx * 2 + 1]);
        return;
    }
    idx -= n_c1;
    if (idx < n_c2) {
        wq[OFF_L0C2_0 + idx] = f2bs(w2_0[idx * 2]);
        wq[OFF_L0C2_1 + idx] = f2bs(w2_0[idx * 2 + 1]);
        return;
    }
    idx -= n_c2;
    if (idx < 4 * n_c2) {
        const int li = idx / n_c2, j = idx - li * n_c2;
        wq[OFF_C1B + li * 32768 + j]         = f2bs(W1[(li * n_c2 + j) * 2]);
        wq[OFF_C1B + li * 32768 + 16384 + j] = f2bs(W1[(li * n_c2 + j) * 2 + 1]);
        return;
    }
    idx -= 4 * n_c2;
    if (idx < 4 * n_c2) {
        const int li = idx / n_c2, j = idx - li * n_c2;
        wq[OFF_C2B + li * 32768 + j]         = f2bs(W2[(li * n_c2 + j) * 2]);
        wq[OFF_C2B + li * 32768 + 16384 + j] = f2bs(W2[(li * n_c2 + j) * 2 + 1]);
        return;
    }
    idx -= 4 * n_c2;
    if (idx < n_c1) wq[OFF_DS + idx] = f2bs(ds_w[idx]);
}

// ---------------------------------------------------------------------------
extern "C" void kernel_launch(void* const* d_in, const int* in_sizes, int n_in,
                              void* d_out, int out_size, void* d_ws, size_t ws_size,
                              hipStream_t stream) {
    const float* x_in = (const float*)d_in[0];
    const float* w1_0 = (const float*)d_in[1];
    const float* b1_0 = (const float*)d_in[2];
    const float* w2_0 = (const float*)d_in[3];
    const float* b2_0 = (const float*)d_in[4];
    const float* ds_w = (const float*)d_in[5];
    const float* ds_b = (const float*)d_in[6];
    const float* W1   = (const float*)d_in[7];
    const float* B1   = (const float*)d_in[8];
    const float* W2   = (const float*)d_in[9];
    const float* B2   = (const float*)d_in[10];
    float* out = (float*)d_out;

    short* wq = (short*)d_ws;   // 624 KB plain weight bank

    (void)hipFuncSetAttribute((const void*)tcn_fused,
                              hipFuncAttributeMaxDynamicSharedMemorySize, LDS_BYTES);

    prep_w<<<dim3(640), 256, 0, stream>>>(w1_0, w2_0, ds_w, W1, W2, wq);
    tcn_fused<<<dim3(32, 16), dim3(1024), LDS_BYTES, stream>>>(
        x_in, wq, b1_0, b2_0, ds_b, B1, B2, out);
}

// Round 4
// 176.308 us; speedup vs baseline: 1.3977x; 1.3977x over previous
//
#include <hip/hip_runtime.h>
#include <hip/hip_bf16.h>
#include <math.h>

// Fully-fused TCN, R13: fragment-major LDS tiling (lane-linear ds_reads).
// R12 (weights->VGPR from global) regressed 118->183: 4x redundant L2 weight
// traffic through the VMEM pipe. Reverted to R11's LDS-staged weight pipeline.
// R11 budget: LDS reads ~73K cyc + 29K conflict cyc per block-gen of 141K
// (~70% LDS-bound). This round re-tiles BOTH activation and weight LDS into
// MFMA fragment order:
//   idx(row,ci) = (row>>4)*2048 + (ci>>5)*512 + ((ci>>3)&3)*128 + (row&15)*8 + (ci&7)
// so every wave b128 operand read is base + lane*16B — linear 1KB, 8-cycle,
// conflict-free for ALL dilation offsets (slot index (l16-d)&15 is bijective;
// split blocks are 4KB apart = same bank phase). Weights pre-tiled in prep_w,
// staged linearly via global_load_lds (unchanged), preloaded once per tap into
// wf[2][KCH] registers. No swizzle macro, minimal address VALU.
// LDS = 2x(192x128) act + 2x(128x128) weights = 163840 B (160 KiB), 16 waves.

typedef __attribute__((ext_vector_type(8))) short short8;
typedef __attribute__((ext_vector_type(4))) short short4v;
typedef __attribute__((ext_vector_type(4))) float floatx4;

#define S_LEN 4096
#define ROWS 192                   // 64 halo + 128 outputs (12 row-blocks)
#define AREG (ROWS * 128)          // 24576 shorts per activation region
#define WBUF (128 * 128)           // 16384 shorts per weight buffer (32 KB)
#define LDS_BYTES ((2 * AREG + 2 * WBUF) * 2)   // 163840 B

// weight bank offsets (shorts) — each tap contiguous, fragment-major tiled
#define OFF_DS     0
#define OFF_L0C1_0 8192
#define OFF_L0C1_1 16384
#define OFF_L0C2_0 24576
#define OFF_L0C2_1 40960
#define OFF_C1B    57344      // + lvl*32768 ; tap1 at +16384
#define OFF_C2B    188416     // + lvl*32768 ; tap1 at +16384

__device__ __forceinline__ float elu_f(float v) {
    return v > 0.0f ? v : (__expf(v) - 1.0f);
}
__device__ __forceinline__ short f2bs(float v) {
    __hip_bfloat16 h = __float2bfloat16(v);
    return *reinterpret_cast<short*>(&h);
}
__device__ __forceinline__ float bs2f(short s) {
    __hip_bfloat16 h = *reinterpret_cast<__hip_bfloat16*>(&s);
    return __bfloat162float(h);
}
__device__ __forceinline__ short4v pack4(const floatx4 v) {
    __hip_bfloat162 p0 = __float22bfloat162_rn(make_float2(v[0], v[1]));
    __hip_bfloat162 p1 = __float22bfloat162_rn(make_float2(v[2], v[3]));
    short4v r;
    r[0] = ((const short*)&p0)[0]; r[1] = ((const short*)&p0)[1];
    r[2] = ((const short*)&p1)[0]; r[3] = ((const short*)&p1)[1];
    return r;
}

// async 16B global->LDS copy (wave-uniform LDS base + lane*16 hardware rule)
__device__ __forceinline__ void gld_lds16(const void* g, void* l) {
    __builtin_amdgcn_global_load_lds(
        (const __attribute__((address_space(1))) void*)g,
        (__attribute__((address_space(3))) void*)l, 16, 0, 0);
}

// Issue async loads of one pre-tiled weight tap (NSH shorts) into LDS.
// 16 waves x NI insts x 1KB. Completion is published by the NEXT __syncthreads.
template<int NSH>
__device__ __forceinline__ void stage_async(short* __restrict__ lds,
                                            const short* __restrict__ src,
                                            int wave, int lane)
{
    constexpr int NI = (NSH * 2) / 16384;  // insts per wave (1 KB each, 16 waves)
    const char* g = (const char*)src + wave * 1024 + lane * 16;
    char* l = (char*)lds + wave * 1024;    // wave-uniform base
    #pragma unroll
    for (int i = 0; i < NI; ++i)
        gld_lds16(g + i * 16384, l + i * 16384);
}

// ---------------------------------------------------------------------------
// One tap's MFMAs: acc[mt][nt] += W[co][ci] * X[r - doff][ci].
// Weight fragments preloaded once per tap; activation reads are lane-linear
// 1KB ds_read_b128 bursts (conflict-free for any doff).
// ---------------------------------------------------------------------------
template<int KCH>
__device__ __forceinline__ void conv_tap(
    const short* __restrict__ Lin, const short* __restrict__ Lw,
    const int doff, const int srow, const int l16, const int quad,
    const int cobase, floatx4 (&acc)[2][3])
{
    // preload this wave's weight fragments (2*KCH x b128, lane-linear)
    const short* wb = Lw + (cobase >> 4) * (KCH * 512) + quad * 128 + l16 * 8;
    short8 wf[2][4];
    #pragma unroll
    for (int mt = 0; mt < 2; ++mt)
        #pragma unroll
        for (int kc = 0; kc < KCH; ++kc)
            wf[mt][kc] = *(const short8*)(wb + mt * (KCH * 512) + kc * 512);

    #pragma unroll
    for (int nt = 0; nt < 3; ++nt) {
        int r = srow + nt * 16 + l16 - doff;
        if (r < 0) r = 0;              // clamped rows never feed valid outputs
        const short* ab = Lin + (r >> 4) * 2048 + (r & 15) * 8 + quad * 128;
        #pragma unroll
        for (int kc = 0; kc < KCH; ++kc) {
            const short8 bf = *(const short8*)(ab + kc * 512);
            #pragma unroll
            for (int mt = 0; mt < 2; ++mt)
                acc[mt][nt] = __builtin_amdgcn_mfma_f32_16x16x32_bf16(wf[mt][kc], bf, acc[mt][nt], 0, 0, 0);
        }
    }
}

__device__ __forceinline__ void zero_acc(floatx4 (&acc)[2][3]) {
    #pragma unroll
    for (int mt = 0; mt < 2; ++mt)
        #pragma unroll
        for (int nt = 0; nt < 3; ++nt) acc[mt][nt] = {0.f, 0.f, 0.f, 0.f};
}

// ---------------------------------------------------------------------------
// Packed epilogue (fragment-major addresses). MODE 0: elu(acc+b); 1: acc+b;
// 2: elu(elu(acc+b)+dst) in place (own-lane read+write).
// ---------------------------------------------------------------------------
template<int MODE, bool KEEP>
__device__ __forceinline__ void store_tile(short* __restrict__ dst,
    const floatx4 (&acc)[2][3], const float* __restrict__ bias,
    int cobase, int srow, int l16, int quad, int zero_below, short4v* keep)
{
    #pragma unroll
    for (int mt = 0; mt < 2; ++mt) {
        const int co4 = cobase + mt * 16 + quad * 4;
        const int cterm = (co4 >> 5) * 512 + ((co4 >> 3) & 3) * 128 + (co4 & 7);
        const floatx4 bb = *(const floatx4*)(bias + co4);
        #pragma unroll
        for (int nt = 0; nt < 3; ++nt) {
            const int sl = srow + nt * 16 + l16;
            short* p = dst + (sl >> 4) * 2048 + (sl & 15) * 8 + cterm;
            floatx4 y;
            #pragma unroll
            for (int rr = 0; rr < 4; ++rr) {
                float v = acc[mt][nt][rr] + bb[rr];
                if (MODE != 1) v = elu_f(v);
                y[rr] = v;
            }
            if (MODE == 2) {
                const short4v old = *(const short4v*)p;
                #pragma unroll
                for (int rr = 0; rr < 4; ++rr) y[rr] = elu_f(y[rr] + bs2f(old[rr]));
            }
            if (sl < zero_below) y = {0.f, 0.f, 0.f, 0.f};
            const short4v pk = pack4(y);
            *(short4v*)p = pk;
            if (KEEP) keep[mt * 3 + nt] = pk;
        }
    }
}

// ---------------------------------------------------------------------------
__global__ __launch_bounds__(1024, 4)
void tcn_fused(const float* __restrict__ x,     // fp32 [16,64,4096] channel-first
               const short* __restrict__ wq,
               const float* __restrict__ b1_0, const float* __restrict__ b2_0,
               const float* __restrict__ ds_b, const float* __restrict__ B1,
               const float* __restrict__ B2, float* __restrict__ out)
{
    extern __shared__ short L[];
    short* RA = L;                 // T buffer (also X staging)
    short* RB = L + AREG;          // D buffer (residual chain)
    short* W0 = L + 2 * AREG;      // weight double-buffer
    short* W1 = L + 2 * AREG + WBUF;

    const int tid  = threadIdx.x;
    const int wave = tid >> 6, lane = tid & 63;
    const int l16  = lane & 15, quad = lane >> 4;
    const int cobase = (wave & 3) * 32;    // 4 co-groups of 32
    const int srow   = (wave >> 2) * 48;   // 4 row-groups of 48
    const int s0  = blockIdx.x * 128;
    const int s0g = s0 - 64;
    const int b   = blockIdx.y;
    const int zb  = (s0 == 0) ? 64 : 0;   // zero rows with global s < 0

    // ---- prologue: issue tap-0 (ds) weight loads, then stage X into RA
    stage_async<8192>(W0, wq + OFF_DS, wave, lane);
    {
        const float* xp = x + (size_t)b * 64 * S_LEN;
        const int ci0 = wave * 4;
        const int cterm = (ci0 >> 5) * 512 + ((ci0 >> 3) & 3) * 128 + (ci0 & 7);
        #pragma unroll
        for (int h = 0; h < 3; ++h) {
            const int r = lane + h * 64;
            const int s = s0g + r;
            short4v pk;
            #pragma unroll
            for (int c4 = 0; c4 < 4; ++c4) {
                const float v = (s >= 0) ? xp[(ci0 + c4) * S_LEN + s] : 0.f;
                pk[c4] = f2bs(v);
            }
            *(short4v*)(RA + (r >> 4) * 2048 + (r & 15) * 8 + cterm) = pk;
        }
    }

    floatx4 acc[2][3];
    short4v x1keep[6];

    // t0: ds (1x1, CIN=64): X(RA) -> D(RB)
    __syncthreads();                               // publishes X + ds weights
    stage_async<8192>(W1, wq + OFF_L0C1_0, wave, lane);
    zero_acc(acc);
    conv_tap<2>(RA, W0, 0, srow, l16, quad, cobase, acc);
    store_tile<1, false>(RB, acc, ds_b, cobase, srow, l16, quad, zb, nullptr);

    // t1: c1_0 k0 (d=1, CIN=64)
    __syncthreads();
    stage_async<8192>(W0, wq + OFF_L0C1_1, wave, lane);
    zero_acc(acc);
    conv_tap<2>(RA, W1, 1, srow, l16, quad, cobase, acc);

    // t2: c1_0 k1 -> T over RA (in-place: extra barrier before overwrite)
    __syncthreads();
    stage_async<16384>(W1, wq + OFF_L0C2_0, wave, lane);
    conv_tap<2>(RA, W0, 0, srow, l16, quad, cobase, acc);
    __syncthreads();                               // all X reads done
    store_tile<0, false>(RA, acc, b1_0, cobase, srow, l16, quad, zb, nullptr);

    // t3: c2_0 k0 (CIN=128)
    __syncthreads();
    stage_async<16384>(W0, wq + OFF_L0C2_1, wave, lane);
    zero_acc(acc);
    conv_tap<4>(RA, W1, 1, srow, l16, quad, cobase, acc);

    // t4: c2_0 k1 -> RB in place (res), keep x1
    __syncthreads();
    stage_async<16384>(W1, wq + OFF_C1B, wave, lane);
    conv_tap<4>(RA, W0, 0, srow, l16, quad, cobase, acc);
    store_tile<2, true>(RB, acc, b2_0, cobase, srow, l16, quad, zb, x1keep);

    // ---- levels 1..3 (d = 2, 4, 8)
    #pragma unroll
    for (int lvl = 0; lvl < 3; ++lvl) {
        const int d = 2 << lvl;
        const short* nc1k1 = wq + OFF_C1B + lvl * 32768 + 16384;
        const short* nc2k0 = wq + OFF_C2B + lvl * 32768;
        const short* nc2k1 = nc2k0 + 16384;
        const short* nnext = wq + OFF_C1B + (lvl + 1) * 32768;  // next level c1k0
        // c1 k0: RB -> acc              (uses W1, prefetch c1k1 -> W0)
        __syncthreads();
        stage_async<16384>(W0, nc1k1, wave, lane);
        zero_acc(acc);
        conv_tap<4>(RB, W1, d, srow, l16, quad, cobase, acc);
        // c1 k1: store T -> RA          (uses W0, prefetch c2k0 -> W1)
        __syncthreads();
        stage_async<16384>(W1, nc2k0, wave, lane);
        conv_tap<4>(RB, W0, 0, srow, l16, quad, cobase, acc);
        store_tile<0, false>(RA, acc, B1 + lvl * 128, cobase, srow, l16, quad, zb, nullptr);
        // c2 k0: RA -> acc              (uses W1, prefetch c2k1 -> W0)
        __syncthreads();
        stage_async<16384>(W0, nc2k1, wave, lane);
        zero_acc(acc);
        conv_tap<4>(RA, W1, d, srow, l16, quad, cobase, acc);
        // c2 k1: RB in place (res)      (uses W0, prefetch next c1k0 -> W1)
        __syncthreads();
        stage_async<16384>(W1, nnext, wave, lane);
        conv_tap<4>(RA, W0, 0, srow, l16, quad, cobase, acc);
        store_tile<2, false>(RB, acc, B2 + lvl * 128, cobase, srow, l16, quad, zb, nullptr);
    }

    // ---- level 4 (d=16)
    // t17: c1 k0 (uses W1, prefetch c1k1 -> W0)
    __syncthreads();
    stage_async<16384>(W0, wq + OFF_C1B + 3 * 32768 + 16384, wave, lane);
    zero_acc(acc);
    conv_tap<4>(RB, W1, 16, srow, l16, quad, cobase, acc);
    // t18: c1 k1 -> RA (uses W0, prefetch c2k0 -> W1)
    __syncthreads();
    stage_async<16384>(W1, wq + OFF_C2B + 3 * 32768, wave, lane);
    conv_tap<4>(RB, W0, 0, srow, l16, quad, cobase, acc);
    store_tile<0, false>(RA, acc, B1 + 384, cobase, srow, l16, quad, zb, nullptr);
    // t19: c2 k0 (uses W1, prefetch c2k1 -> W0)
    __syncthreads();
    stage_async<16384>(W0, wq + OFF_C2B + 3 * 32768 + 16384, wave, lane);
    zero_acc(acc);
    conv_tap<4>(RA, W1, 16, srow, l16, quad, cobase, acc);
    // t20: c2 k1 (uses W0) -> final epilogue, rows 64..191 only
    __syncthreads();
    conv_tap<4>(RA, W0, 0, srow, l16, quad, cobase, acc);
    {
        #pragma unroll
        for (int mt = 0; mt < 2; ++mt) {
            const int co4 = cobase + mt * 16 + quad * 4;
            const int cterm = (co4 >> 5) * 512 + ((co4 >> 3) & 3) * 128 + (co4 & 7);
            const floatx4 bb = *(const floatx4*)(B2 + 384 + co4);
            #pragma unroll
            for (int nt = 0; nt < 3; ++nt) {
                if (srow + nt * 16 < 64) continue;     // halo rows: no output
                const int sl = srow + nt * 16 + l16;
                const int sg = s0g + sl;
                const int off = (sl >> 4) * 2048 + (sl & 15) * 8 + cterm;
                const short4v res = *(const short4v*)(RB + off);
                const short4v k   = x1keep[mt * 3 + nt];
                #pragma unroll
                for (int rr = 0; rr < 4; ++rr) {
                    float y = elu_f(acc[mt][nt][rr] + bb[rr]);
                    y = elu_f(y + bs2f(res[rr]));
                    y += bs2f(k[rr]);
                    out[((size_t)(b * 128 + co4 + rr)) * S_LEN + sg] = y;
                }
            }
        }
    }
}

// ---------------------------------------------------------------------------
// weights fp32 [co][ci][k] -> bf16 tap matrices, FRAGMENT-MAJOR tiled:
// widx(co,ci) = (co>>4)*(KC*512) + (ci>>5)*512 + ((ci>>3)&3)*128 + (co&15)*8 + (ci&7)
// so the linear global_load_lds copy produces lane-linear LDS fragments.
// ---------------------------------------------------------------------------
__device__ __forceinline__ int widx(int co, int ci, int KC) {
    return (co >> 4) * (KC * 512) + (ci >> 5) * 512 + ((ci >> 3) & 3) * 128
         + (co & 15) * 8 + (ci & 7);
}

__global__ __launch_bounds__(256)
void prep_w(const float* __restrict__ w1_0, const float* __restrict__ w2_0,
            const float* __restrict__ ds_w, const float* __restrict__ W1,
            const float* __restrict__ W2, short* __restrict__ wq)
{
    int idx = blockIdx.x * 256 + threadIdx.x;
    const int n_c1 = 128 * 64;
    const int n_c2 = 128 * 128;
    if (idx < n_c1) {
        const int co = idx >> 6, ci = idx & 63;
        const int d = widx(co, ci, 2);
        wq[OFF_L0C1_0 + d] = f2bs(w1_0[idx * 2]);
        wq[OFF_L0C1_1 + d] = f2bs(w1_0[idx * 2 + 1]);
        return;
    }
    idx -= n_c1;
    if (idx < n_c2) {
        const int co = idx >> 7, ci = idx & 127;
        const int d = widx(co, ci, 4);
        wq[OFF_L0C2_0 + d] = f2bs(w2_0[idx * 2]);
        wq[OFF_L0C2_1 + d] = f2bs(w2_0[idx * 2 + 1]);
        return;
    }
    idx -= n_c2;
    if (idx < 4 * n_c2) {
        const int li = idx / n_c2, j = idx - li * n_c2;
        const int co = j >> 7, ci = j & 127;
        const int d = widx(co, ci, 4);
        wq[OFF_C1B + li * 32768 + d]         = f2bs(W1[(li * n_c2 + j) * 2]);
        wq[OFF_C1B + li * 32768 + 16384 + d] = f2bs(W1[(li * n_c2 + j) * 2 + 1]);
        return;
    }
    idx -= 4 * n_c2;
    if (idx < 4 * n_c2) {
        const int li = idx / n_c2, j = idx - li * n_c2;
        const int co = j >> 7, ci = j & 127;
        const int d = widx(co, ci, 4);
        wq[OFF_C2B + li * 32768 + d]         = f2bs(W2[(li * n_c2 + j) * 2]);
        wq[OFF_C2B + li * 32768 + 16384 + d] = f2bs(W2[(li * n_c2 + j) * 2 + 1]);
        return;
    }
    idx -= 4 * n_c2;
    if (idx < n_c1) {
        const int co = idx >> 6, ci = idx & 63;
        wq[OFF_DS + widx(co, ci, 2)] = f2bs(ds_w[idx]);
    }
}

// ---------------------------------------------------------------------------
extern "C" void kernel_launch(void* const* d_in, const int* in_sizes, int n_in,
                              void* d_out, int out_size, void* d_ws, size_t ws_size,
                              hipStream_t stream) {
    const float* x_in = (const float*)d_in[0];
    const float* w1_0 = (const float*)d_in[1];
    const float* b1_0 = (const float*)d_in[2];
    const float* w2_0 = (const float*)d_in[3];
    const float* b2_0 = (const float*)d_in[4];
    const float* ds_w = (const float*)d_in[5];
    const float* ds_b = (const float*)d_in[6];
    const float* W1   = (const float*)d_in[7];
    const float* B1   = (const float*)d_in[8];
    const float* W2   = (const float*)d_in[9];
    const float* B2   = (const float*)d_in[10];
    float* out = (float*)d_out;

    short* wq = (short*)d_ws;   // 624 KB fragment-major weight bank

    (void)hipFuncSetAttribute((const void*)tcn_fused,
                              hipFuncAttributeMaxDynamicSharedMemorySize, LDS_BYTES);

    prep_w<<<dim3(640), 256, 0, stream>>>(w1_0, w2_0, ds_w, W1, W2, wq);
    tcn_fused<<<dim3(32, 16), dim3(1024), LDS_BYTES, stream>>>(
        x_in, wq, b1_0, b2_0, ds_b, B1, B2, out);
}

// Round 5
// 171.583 us; speedup vs baseline: 1.4362x; 1.0275x over previous
//
#include <hip/hip_runtime.h>
#include <hip/hip_bf16.h>
#include <math.h>

// Fully-fused TCN, R14: VALU/traffic polish on the R13 fragment-major design.
// R13 verified: conflicts 1.49e7->2.26e6, 105us. Budget now: LDS reads ~60%
// (floor), SIMD issue (VALU+MFMA) ~73% busy, epilogues = biggest VALU chunk.
// Changes (no layout change, no pipeline change):
//  - ds output D kept in registers (dk, bf16) instead of LDS round-trip:
//    removes a store_tile + re-read, and the in-place hazard barrier (22->21).
//    Buffer roles: RA = level io (in-place lane-local residual), RB = T.
//  - activation fragment offsets precomputed per dilation (aoff0/aoffd),
//    not per tap (~630 -> ~250 VALU addr ops per wave per gen).
//  - halo zeroing via wave-uniform branch (sl<64 uniform per (srow,nt)).
// LDS = 2x(192x128) act + 2x(128x128) weights = 163840 B (160 KiB), 16 waves.

typedef __attribute__((ext_vector_type(8))) short short8;
typedef __attribute__((ext_vector_type(4))) short short4v;
typedef __attribute__((ext_vector_type(4))) float floatx4;

#define S_LEN 4096
#define ROWS 192                   // 64 halo + 128 outputs (12 row-blocks)
#define AREG (ROWS * 128)          // 24576 shorts per activation region
#define WBUF (128 * 128)           // 16384 shorts per weight buffer (32 KB)
#define LDS_BYTES ((2 * AREG + 2 * WBUF) * 2)   // 163840 B

// weight bank offsets (shorts) — each tap contiguous, fragment-major tiled
#define OFF_DS     0
#define OFF_L0C1_0 8192
#define OFF_L0C1_1 16384
#define OFF_L0C2_0 24576
#define OFF_L0C2_1 40960
#define OFF_C1B    57344      // + lvl*32768 ; tap1 at +16384
#define OFF_C2B    188416     // + lvl*32768 ; tap1 at +16384

__device__ __forceinline__ float elu_f(float v) {
    return v > 0.0f ? v : (__expf(v) - 1.0f);
}
__device__ __forceinline__ short f2bs(float v) {
    __hip_bfloat16 h = __float2bfloat16(v);
    return *reinterpret_cast<short*>(&h);
}
__device__ __forceinline__ float bs2f(short s) {
    __hip_bfloat16 h = *reinterpret_cast<__hip_bfloat16*>(&s);
    return __bfloat162float(h);
}
__device__ __forceinline__ short4v pack4(const floatx4 v) {
    __hip_bfloat162 p0 = __float22bfloat162_rn(make_float2(v[0], v[1]));
    __hip_bfloat162 p1 = __float22bfloat162_rn(make_float2(v[2], v[3]));
    short4v r;
    r[0] = ((const short*)&p0)[0]; r[1] = ((const short*)&p0)[1];
    r[2] = ((const short*)&p1)[0]; r[3] = ((const short*)&p1)[1];
    return r;
}

// async 16B global->LDS copy (wave-uniform LDS base + lane*16 hardware rule)
__device__ __forceinline__ void gld_lds16(const void* g, void* l) {
    __builtin_amdgcn_global_load_lds(
        (const __attribute__((address_space(1))) void*)g,
        (__attribute__((address_space(3))) void*)l, 16, 0, 0);
}

// Issue async loads of one pre-tiled weight tap (NSH shorts) into LDS.
// 16 waves x NI insts x 1KB. Completion is published by the NEXT __syncthreads.
template<int NSH>
__device__ __forceinline__ void stage_async(short* __restrict__ lds,
                                            const short* __restrict__ src,
                                            int wave, int lane)
{
    constexpr int NI = (NSH * 2) / 16384;  // insts per wave (1 KB each, 16 waves)
    const char* g = (const char*)src + wave * 1024 + lane * 16;
    char* l = (char*)lds + wave * 1024;    // wave-uniform base
    #pragma unroll
    for (int i = 0; i < NI; ++i)
        gld_lds16(g + i * 16384, l + i * 16384);
}

// activation fragment offsets for one dilation (per nt), clamped at row 0
__device__ __forceinline__ void mkoff(int (&o)[3], int srow, int l16, int quad, int d) {
    #pragma unroll
    for (int nt = 0; nt < 3; ++nt) {
        int r = srow + nt * 16 + l16 - d;
        if (r < 0) r = 0;              // clamped rows never feed valid outputs
        o[nt] = (r >> 4) * 2048 + (r & 15) * 8 + quad * 128;
    }
}

// ---------------------------------------------------------------------------
// One tap's MFMAs: acc[mt][nt] += W[co][ci] * X[r - d][ci].
// Lw is already offset to this wave's fragment base; ao = precomputed offsets.
// ---------------------------------------------------------------------------
template<int KCH>
__device__ __forceinline__ void conv_tap(const short* __restrict__ Lin,
                                         const short* __restrict__ Lw,
                                         const int (&ao)[3], floatx4 (&acc)[2][3])
{
    short8 wf[2][KCH];
    #pragma unroll
    for (int mt = 0; mt < 2; ++mt)
        #pragma unroll
        for (int kc = 0; kc < KCH; ++kc)
            wf[mt][kc] = *(const short8*)(Lw + mt * (KCH * 512) + kc * 512);
    #pragma unroll
    for (int nt = 0; nt < 3; ++nt) {
        const short* ab = Lin + ao[nt];
        #pragma unroll
        for (int kc = 0; kc < KCH; ++kc) {
            const short8 bf = *(const short8*)(ab + kc * 512);
            #pragma unroll
            for (int mt = 0; mt < 2; ++mt)
                acc[mt][nt] = __builtin_amdgcn_mfma_f32_16x16x32_bf16(wf[mt][kc], bf, acc[mt][nt], 0, 0, 0);
        }
    }
}

__device__ __forceinline__ void zero_acc(floatx4 (&acc)[2][3]) {
    #pragma unroll
    for (int mt = 0; mt < 2; ++mt)
        #pragma unroll
        for (int nt = 0; nt < 3; ++nt) acc[mt][nt] = {0.f, 0.f, 0.f, 0.f};
}

// ---------------------------------------------------------------------------
__global__ __launch_bounds__(1024, 4)
void tcn_fused(const float* __restrict__ x,     // fp32 [16,64,4096] channel-first
               const short* __restrict__ wq,
               const float* __restrict__ b1_0, const float* __restrict__ b2_0,
               const float* __restrict__ ds_b, const float* __restrict__ B1,
               const float* __restrict__ B2, float* __restrict__ out)
{
    extern __shared__ short L[];
    short* RA = L;                 // level io (X, then x1, ... in-place)
    short* RB = L + AREG;          // T scratch
    short* W0 = L + 2 * AREG;      // weight double-buffer
    short* W1 = L + 2 * AREG + WBUF;

    const int tid  = threadIdx.x;
    const int wave = tid >> 6, lane = tid & 63;
    const int l16  = lane & 15, quad = lane >> 4;
    const int cobase = (wave & 3) * 32;    // 4 co-groups of 32
    const int srow   = (wave >> 2) * 48;   // 4 row-groups of 48
    const int s0  = blockIdx.x * 128;
    const int s0g = s0 - 64;
    const int b   = blockIdx.y;
    const bool zb = (s0 == 0);             // zero rows with global s < 0

    // per-wave constant addressing
    const int wqb2 = (cobase >> 4) * 1024 + quad * 128 + l16 * 8;  // KCH=2 base
    const int wqb4 = (cobase >> 4) * 2048 + quad * 128 + l16 * 8;  // KCH=4 base
    int aoff0[3], aoffd[3];
    mkoff(aoff0, srow, l16, quad, 0);
    // store offsets (lane-local): sb[nt] + ct[mt]
    int sb[3];
    #pragma unroll
    for (int nt = 0; nt < 3; ++nt) {
        const int sl = srow + nt * 16 + l16;
        sb[nt] = (sl >> 4) * 2048 + (sl & 15) * 8;
    }
    int ct[2];
    #pragma unroll
    for (int mt = 0; mt < 2; ++mt) {
        const int co4 = cobase + mt * 16 + quad * 4;
        ct[mt] = (co4 >> 5) * 512 + ((co4 >> 3) & 3) * 128 + (co4 & 7);
    }
    // uniform halo-zero flags per nt (srow + nt*16 is a multiple of 16)
    bool zr[3];
    #pragma unroll
    for (int nt = 0; nt < 3; ++nt) zr[nt] = zb && (srow + nt * 16 < 64);

    floatx4 acc[2][3];
    short4v x1keep[6];
    short4v dk[6];

    // ---- prologue: issue tap-0 (ds) weight loads, then stage X into RA
    stage_async<8192>(W0, wq + OFF_DS, wave, lane);
    {
        const float* xp = x + (size_t)b * 64 * S_LEN;
        const int ci0 = wave * 4;
        const int cterm = (ci0 >> 5) * 512 + ((ci0 >> 3) & 3) * 128 + (ci0 & 7);
        #pragma unroll
        for (int h = 0; h < 3; ++h) {
            const int r = lane + h * 64;
            const int s = s0g + r;
            short4v pk;
            #pragma unroll
            for (int c4 = 0; c4 < 4; ++c4) {
                const float v = (s >= 0) ? xp[(ci0 + c4) * S_LEN + s] : 0.f;
                pk[c4] = f2bs(v);
            }
            *(short4v*)(RA + (r >> 4) * 2048 + (r & 15) * 8 + cterm) = pk;
        }
    }
    __syncthreads();                               // B0: X + ds weights

    // ---- t0: ds (1x1, CIN=64): RA -> dk registers (no LDS round-trip)
    stage_async<8192>(W1, wq + OFF_L0C1_0, wave, lane);
    zero_acc(acc);
    conv_tap<2>(RA, W0 + wqb2, aoff0, acc);
    #pragma unroll
    for (int mt = 0; mt < 2; ++mt) {
        const int co4 = cobase + mt * 16 + quad * 4;
        const floatx4 bb = *(const floatx4*)(ds_b + co4);
        #pragma unroll
        for (int nt = 0; nt < 3; ++nt) {
            floatx4 y = acc[mt][nt] + bb;
            if (zr[nt]) y = {0.f, 0.f, 0.f, 0.f};
            dk[mt * 3 + nt] = pack4(y);
        }
    }
    __syncthreads();                               // B1: c1k0 weights

    // ---- t1: c1_0 k0 (d=1, CIN=64)
    stage_async<8192>(W0, wq + OFF_L0C1_1, wave, lane);
    mkoff(aoffd, srow, l16, quad, 1);
    zero_acc(acc);
    conv_tap<2>(RA, W1 + wqb2, aoffd, acc);
    __syncthreads();                               // B2: c1k1 weights

    // ---- t2: c1_0 k1 -> T into RB (no in-place hazard)
    stage_async<16384>(W1, wq + OFF_L0C2_0, wave, lane);
    conv_tap<2>(RA, W0 + wqb2, aoff0, acc);
    #pragma unroll
    for (int mt = 0; mt < 2; ++mt) {
        const int co4 = cobase + mt * 16 + quad * 4;
        const floatx4 bb = *(const floatx4*)(b1_0 + co4);
        #pragma unroll
        for (int nt = 0; nt < 3; ++nt) {
            floatx4 y = acc[mt][nt] + bb;
            #pragma unroll
            for (int rr = 0; rr < 4; ++rr) y[rr] = elu_f(y[rr]);
            if (zr[nt]) y = {0.f, 0.f, 0.f, 0.f};
            *(short4v*)(RB + sb[nt] + ct[mt]) = pack4(y);
        }
    }
    __syncthreads();                               // B3: T + c2k0 weights

    // ---- t3: c2_0 k0 (CIN=128), reads T(RB)
    stage_async<16384>(W0, wq + OFF_L0C2_1, wave, lane);
    zero_acc(acc);
    conv_tap<4>(RB, W1 + wqb4, aoffd, acc);
    __syncthreads();                               // B4: c2k1 weights

    // ---- t4: c2_0 k1 -> x1 into RA (X dead); res = dk; keep x1
    stage_async<16384>(W1, wq + OFF_C1B, wave, lane);
    conv_tap<4>(RB, W0 + wqb4, aoff0, acc);
    #pragma unroll
    for (int mt = 0; mt < 2; ++mt) {
        const int co4 = cobase + mt * 16 + quad * 4;
        const floatx4 bb = *(const floatx4*)(b2_0 + co4);
        #pragma unroll
        for (int nt = 0; nt < 3; ++nt) {
            floatx4 y = acc[mt][nt] + bb;
            const short4v d4 = dk[mt * 3 + nt];
            #pragma unroll
            for (int rr = 0; rr < 4; ++rr) {
                y[rr] = elu_f(y[rr]);
                y[rr] = elu_f(y[rr] + bs2f(d4[rr]));
            }
            if (zr[nt]) y = {0.f, 0.f, 0.f, 0.f};
            const short4v pk = pack4(y);
            *(short4v*)(RA + sb[nt] + ct[mt]) = pk;
            x1keep[mt * 3 + nt] = pk;
        }
    }
    __syncthreads();                               // B5: x1 + L1 c1k0 weights

    // ---- levels 1..3 (d = 2, 4, 8): io in RA (in-place), T in RB
    #pragma unroll
    for (int lvl = 0; lvl < 3; ++lvl) {
        const int d = 2 << lvl;
        mkoff(aoffd, srow, l16, quad, d);
        // c1 k0 (W1), prefetch c1k1 -> W0
        stage_async<16384>(W0, wq + OFF_C1B + lvl * 32768 + 16384, wave, lane);
        zero_acc(acc);
        conv_tap<4>(RA, W1 + wqb4, aoffd, acc);
        __syncthreads();
        // c1 k1 (W0) -> T into RB; prefetch c2k0 -> W1
        stage_async<16384>(W1, wq + OFF_C2B + lvl * 32768, wave, lane);
        conv_tap<4>(RA, W0 + wqb4, aoff0, acc);
        #pragma unroll
        for (int mt = 0; mt < 2; ++mt) {
            const int co4 = cobase + mt * 16 + quad * 4;
            const floatx4 bb = *(const floatx4*)(B1 + lvl * 128 + co4);
            #pragma unroll
            for (int nt = 0; nt < 3; ++nt) {
                floatx4 y = acc[mt][nt] + bb;
                #pragma unroll
                for (int rr = 0; rr < 4; ++rr) y[rr] = elu_f(y[rr]);
                if (zr[nt]) y = {0.f, 0.f, 0.f, 0.f};
                *(short4v*)(RB + sb[nt] + ct[mt]) = pack4(y);
            }
        }
        __syncthreads();
        // c2 k0 (W1), reads T(RB); prefetch c2k1 -> W0
        stage_async<16384>(W0, wq + OFF_C2B + lvl * 32768 + 16384, wave, lane);
        zero_acc(acc);
        conv_tap<4>(RB, W1 + wqb4, aoffd, acc);
        __syncthreads();
        // c2 k1 (W0) -> out into RA in-place (lane-local res); prefetch next
        stage_async<16384>(W1, wq + OFF_C1B + (lvl + 1) * 32768, wave, lane);
        conv_tap<4>(RB, W0 + wqb4, aoff0, acc);
        #pragma unroll
        for (int mt = 0; mt < 2; ++mt) {
            const int co4 = cobase + mt * 16 + quad * 4;
            const floatx4 bb = *(const floatx4*)(B2 + lvl * 128 + co4);
            #pragma unroll
            for (int nt = 0; nt < 3; ++nt) {
                short* p = RA + sb[nt] + ct[mt];
                const short4v old = *(const short4v*)p;
                floatx4 y = acc[mt][nt] + bb;
                #pragma unroll
                for (int rr = 0; rr < 4; ++rr) {
                    y[rr] = elu_f(y[rr]);
                    y[rr] = elu_f(y[rr] + bs2f(old[rr]));
                }
                if (zr[nt]) y = {0.f, 0.f, 0.f, 0.f};
                *(short4v*)p = pack4(y);
            }
        }
        __syncthreads();
    }

    // ---- level 4 (d=16)
    mkoff(aoffd, srow, l16, quad, 16);
    // c1 k0 (W1), prefetch c1k1 -> W0
    stage_async<16384>(W0, wq + OFF_C1B + 3 * 32768 + 16384, wave, lane);
    zero_acc(acc);
    conv_tap<4>(RA, W1 + wqb4, aoffd, acc);
    __syncthreads();
    // c1 k1 (W0) -> T into RB; prefetch c2k0 -> W1
    stage_async<16384>(W1, wq + OFF_C2B + 3 * 32768, wave, lane);
    conv_tap<4>(RA, W0 + wqb4, aoff0, acc);
    #pragma unroll
    for (int mt = 0; mt < 2; ++mt) {
        const int co4 = cobase + mt * 16 + quad * 4;
        const floatx4 bb = *(const floatx4*)(B1 + 384 + co4);
        #pragma unroll
        for (int nt = 0; nt < 3; ++nt) {
            floatx4 y = acc[mt][nt] + bb;
            #pragma unroll
            for (int rr = 0; rr < 4; ++rr) y[rr] = elu_f(y[rr]);
            if (zr[nt]) y = {0.f, 0.f, 0.f, 0.f};
            *(short4v*)(RB + sb[nt] + ct[mt]) = pack4(y);
        }
    }
    __syncthreads();
    // c2 k0 (W1), reads T(RB); prefetch c2k1 -> W0
    stage_async<16384>(W0, wq + OFF_C2B + 3 * 32768 + 16384, wave, lane);
    zero_acc(acc);
    conv_tap<4>(RB, W1 + wqb4, aoffd, acc);
    __syncthreads();
    // c2 k1 (W0) -> final epilogue, rows 64..191 only; res = RA; + x1keep
    conv_tap<4>(RB, W0 + wqb4, aoff0, acc);
    #pragma unroll
    for (int mt = 0; mt < 2; ++mt) {
        const int co4 = cobase + mt * 16 + quad * 4;
        const floatx4 bb = *(const floatx4*)(B2 + 384 + co4);
        #pragma unroll
        for (int nt = 0; nt < 3; ++nt) {
            if (srow + nt * 16 < 64) continue;     // halo rows: no output
            const int sl = srow + nt * 16 + l16;
            const int sg = s0g + sl;
            const short4v res = *(const short4v*)(RA + sb[nt] + ct[mt]);
            const short4v k   = x1keep[mt * 3 + nt];
            #pragma unroll
            for (int rr = 0; rr < 4; ++rr) {
                float y = elu_f(acc[mt][nt][rr] + bb[rr]);
                y = elu_f(y + bs2f(res[rr]));
                y += bs2f(k[rr]);
                out[((size_t)(b * 128 + co4 + rr)) * S_LEN + sg] = y;
            }
        }
    }
}

// ---------------------------------------------------------------------------
// weights fp32 [co][ci][k] -> bf16 tap matrices, FRAGMENT-MAJOR tiled:
// widx(co,ci) = (co>>4)*(KC*512) + (ci>>5)*512 + ((ci>>3)&3)*128 + (co&15)*8 + (ci&7)
// so the linear global_load_lds copy produces lane-linear LDS fragments.
// ---------------------------------------------------------------------------
__device__ __forceinline__ int widx(int co, int ci, int KC) {
    return (co >> 4) * (KC * 512) + (ci >> 5) * 512 + ((ci >> 3) & 3) * 128
         + (co & 15) * 8 + (ci & 7);
}

__global__ __launch_bounds__(256)
void prep_w(const float* __restrict__ w1_0, const float* __restrict__ w2_0,
            const float* __restrict__ ds_w, const float* __restrict__ W1,
            const float* __restrict__ W2, short* __restrict__ wq)
{
    int idx = blockIdx.x * 256 + threadIdx.x;
    const int n_c1 = 128 * 64;
    const int n_c2 = 128 * 128;
    if (idx < n_c1) {
        const int co = idx >> 6, ci = idx & 63;
        const int d = widx(co, ci, 2);
        wq[OFF_L0C1_0 + d] = f2bs(w1_0[idx * 2]);
        wq[OFF_L0C1_1 + d] = f2bs(w1_0[idx * 2 + 1]);
        return;
    }
    idx -= n_c1;
    if (idx < n_c2) {
        const int co = idx >> 7, ci = idx & 127;
        const int d = widx(co, ci, 4);
        wq[OFF_L0C2_0 + d] = f2bs(w2_0[idx * 2]);
        wq[OFF_L0C2_1 + d] = f2bs(w2_0[idx * 2 + 1]);
        return;
    }
    idx -= n_c2;
    if (idx < 4 * n_c2) {
        const int li = idx / n_c2, j = idx - li * n_c2;
        const int co = j >> 7, ci = j & 127;
        const int d = widx(co, ci, 4);
        wq[OFF_C1B + li * 32768 + d]         = f2bs(W1[(li * n_c2 + j) * 2]);
        wq[OFF_C1B + li * 32768 + 16384 + d] = f2bs(W1[(li * n_c2 + j) * 2 + 1]);
        return;
    }
    idx -= 4 * n_c2;
    if (idx < 4 * n_c2) {
        const int li = idx / n_c2, j = idx - li * n_c2;
        const int co = j >> 7, ci = j & 127;
        const int d = widx(co, ci, 4);
        wq[OFF_C2B + li * 32768 + d]         = f2bs(W2[(li * n_c2 + j) * 2]);
        wq[OFF_C2B + li * 32768 + 16384 + d] = f2bs(W2[(li * n_c2 + j) * 2 + 1]);
        return;
    }
    idx -= 4 * n_c2;
    if (idx < n_c1) {
        const int co = idx >> 6, ci = idx & 63;
        wq[OFF_DS + widx(co, ci, 2)] = f2bs(ds_w[idx]);
    }
}

// ---------------------------------------------------------------------------
extern "C" void kernel_launch(void* const* d_in, const int* in_sizes, int n_in,
                              void* d_out, int out_size, void* d_ws, size_t ws_size,
                              hipStream_t stream) {
    const float* x_in = (const float*)d_in[0];
    const float* w1_0 = (const float*)d_in[1];
    const float* b1_0 = (const float*)d_in[2];
    const float* w2_0 = (const float*)d_in[3];
    const float* b2_0 = (const float*)d_in[4];
    const float* ds_w = (const float*)d_in[5];
    const float* ds_b = (const float*)d_in[6];
    const float* W1   = (const float*)d_in[7];
    const float* B1   = (const float*)d_in[8];
    const float* W2   = (const float*)d_in[9];
    const float* B2   = (const float*)d_in[10];
    float* out = (float*)d_out;

    short* wq = (short*)d_ws;   // 624 KB fragment-major weight bank

    (void)hipFuncSetAttribute((const void*)tcn_fused,
                              hipFuncAttributeMaxDynamicSharedMemorySize, LDS_BYTES);

    prep_w<<<dim3(640), 256, 0, stream>>>(w1_0, w2_0, ds_w, W1, W2, wq);
    tcn_fused<<<dim3(32, 16), dim3(1024), LDS_BYTES, stream>>>(
        x_in, wq, b1_0, b2_0, ds_b, B1, B2, out);
}

// Round 6
// 168.631 us; speedup vs baseline: 1.4613x; 1.0175x over previous
//
#include <hip/hip_runtime.h>
#include <hip/hip_bf16.h>
#include <math.h>

// Fully-fused TCN, R15: dead-row elimination + phase merge + setprio.
// R13/R14 verified: fragment-major LDS (conflicts 6.6x down), 105us, LDS-read
// bound (~60% of cycles). This round removes work instead of shuffling it:
//  - Backward row-requirement analysis: out needs rows>=64 only; propagating
//    through dilations: L2c2>=16, L3c1>=16, L3c2>=32, L4c1>=48, L4c2>=64.
//    At 16-row granularity: row-group 0 fully idle in L4 taps, partial in
//    L2/L3 -> ~8% fewer ds_reads/MFMAs. Stale rows below the threshold are
//    never read downstream (verified per level). srow is readfirstlane'd so
//    the nt-skips are scalar branches, not exec masks.
//  - ds + c1_0k0 merged into one phase (both 16KB taps co-staged in W0):
//    barriers 21 -> 20.
//  - s_setprio(1) around conv_tap body (wave role diversity now exists).
// LDS = 2x(192x128) act + 2x(128x128) weights = 163840 B (160 KiB), 16 waves.

typedef __attribute__((ext_vector_type(8))) short short8;
typedef __attribute__((ext_vector_type(4))) short short4v;
typedef __attribute__((ext_vector_type(4))) float floatx4;

#define S_LEN 4096
#define ROWS 192                   // 64 halo + 128 outputs (12 row-blocks)
#define AREG (ROWS * 128)          // 24576 shorts per activation region
#define WBUF (128 * 128)           // 16384 shorts per weight buffer (32 KB)
#define LDS_BYTES ((2 * AREG + 2 * WBUF) * 2)   // 163840 B

// weight bank offsets (shorts) — each tap contiguous, fragment-major tiled
#define OFF_DS     0
#define OFF_L0C1_0 8192
#define OFF_L0C1_1 16384
#define OFF_L0C2_0 24576
#define OFF_L0C2_1 40960
#define OFF_C1B    57344      // + lvl*32768 ; tap1 at +16384
#define OFF_C2B    188416     // + lvl*32768 ; tap1 at +16384

__device__ __forceinline__ float elu_f(float v) {
    return v > 0.0f ? v : (__expf(v) - 1.0f);
}
__device__ __forceinline__ short f2bs(float v) {
    __hip_bfloat16 h = __float2bfloat16(v);
    return *reinterpret_cast<short*>(&h);
}
__device__ __forceinline__ float bs2f(short s) {
    __hip_bfloat16 h = *reinterpret_cast<__hip_bfloat16*>(&s);
    return __bfloat162float(h);
}
__device__ __forceinline__ short4v pack4(const floatx4 v) {
    __hip_bfloat162 p0 = __float22bfloat162_rn(make_float2(v[0], v[1]));
    __hip_bfloat162 p1 = __float22bfloat162_rn(make_float2(v[2], v[3]));
    short4v r;
    r[0] = ((const short*)&p0)[0]; r[1] = ((const short*)&p0)[1];
    r[2] = ((const short*)&p1)[0]; r[3] = ((const short*)&p1)[1];
    return r;
}

// async 16B global->LDS copy (wave-uniform LDS base + lane*16 hardware rule)
__device__ __forceinline__ void gld_lds16(const void* g, void* l) {
    __builtin_amdgcn_global_load_lds(
        (const __attribute__((address_space(1))) void*)g,
        (__attribute__((address_space(3))) void*)l, 16, 0, 0);
}

// Issue async loads of one pre-tiled weight tap (NSH shorts) into LDS.
template<int NSH>
__device__ __forceinline__ void stage_async(short* __restrict__ lds,
                                            const short* __restrict__ src,
                                            int wave, int lane)
{
    constexpr int NI = (NSH * 2) / 16384;  // insts per wave (1 KB each, 16 waves)
    const char* g = (const char*)src + wave * 1024 + lane * 16;
    char* l = (char*)lds + wave * 1024;    // wave-uniform base
    #pragma unroll
    for (int i = 0; i < NI; ++i)
        gld_lds16(g + i * 16384, l + i * 16384);
}

// activation fragment offsets for one dilation (per nt), clamped at row 0
__device__ __forceinline__ void mkoff(int (&o)[3], int srow, int l16, int quad, int d) {
    #pragma unroll
    for (int nt = 0; nt < 3; ++nt) {
        int r = srow + nt * 16 + l16 - d;
        if (r < 0) r = 0;              // clamped rows never feed valid outputs
        o[nt] = (r >> 4) * 2048 + (r & 15) * 8 + quad * 128;
    }
}

// nt0 = first needed nt for this wave given a row floor (scalar math)
__device__ __forceinline__ int ntfloor(int minrow, int srow) {
    return (minrow > srow) ? ((minrow - srow + 15) >> 4) : 0;
}

// ---------------------------------------------------------------------------
// One tap's MFMAs: acc[mt][nt] += W[co][ci] * X[r - d][ci], nt >= nt0 only.
// ---------------------------------------------------------------------------
template<int KCH>
__device__ __forceinline__ void conv_tap(const short* __restrict__ Lin,
                                         const short* __restrict__ Lw,
                                         const int (&ao)[3], floatx4 (&acc)[2][3],
                                         const int nt0)
{
    if (nt0 >= 3) return;                  // whole wave idle this tap
    short8 wf[2][KCH];
    #pragma unroll
    for (int mt = 0; mt < 2; ++mt)
        #pragma unroll
        for (int kc = 0; kc < KCH; ++kc)
            wf[mt][kc] = *(const short8*)(Lw + mt * (KCH * 512) + kc * 512);
    __builtin_amdgcn_s_setprio(1);
    #pragma unroll
    for (int nt = 0; nt < 3; ++nt) {
        if (nt < nt0) continue;
        const short* ab = Lin + ao[nt];
        #pragma unroll
        for (int kc = 0; kc < KCH; ++kc) {
            const short8 bf = *(const short8*)(ab + kc * 512);
            #pragma unroll
            for (int mt = 0; mt < 2; ++mt)
                acc[mt][nt] = __builtin_amdgcn_mfma_f32_16x16x32_bf16(wf[mt][kc], bf, acc[mt][nt], 0, 0, 0);
        }
    }
    __builtin_amdgcn_s_setprio(0);
}

__device__ __forceinline__ void zero_acc(floatx4 (&acc)[2][3]) {
    #pragma unroll
    for (int mt = 0; mt < 2; ++mt)
        #pragma unroll
        for (int nt = 0; nt < 3; ++nt) acc[mt][nt] = {0.f, 0.f, 0.f, 0.f};
}

// ---------------------------------------------------------------------------
__global__ __launch_bounds__(1024, 4)
void tcn_fused(const float* __restrict__ x,     // fp32 [16,64,4096] channel-first
               const short* __restrict__ wq,
               const float* __restrict__ b1_0, const float* __restrict__ b2_0,
               const float* __restrict__ ds_b, const float* __restrict__ B1,
               const float* __restrict__ B2, float* __restrict__ out)
{
    extern __shared__ short L[];
    short* RA = L;                 // level io (X, then x1, ... in-place)
    short* RB = L + AREG;          // T scratch
    short* W0 = L + 2 * AREG;      // weight double-buffer
    short* W1 = L + 2 * AREG + WBUF;

    const int tid  = threadIdx.x;
    const int wave = __builtin_amdgcn_readfirstlane(tid >> 6);   // scalar
    const int lane = tid & 63;
    const int l16  = lane & 15, quad = lane >> 4;
    const int cobase = (wave & 3) * 32;    // 4 co-groups of 32   (scalar)
    const int srow   = (wave >> 2) * 48;   // 4 row-groups of 48  (scalar)
    const int s0  = blockIdx.x * 128;
    const int s0g = s0 - 64;
    const int b   = blockIdx.y;
    const bool zb = (s0 == 0);             // zero rows with global s < 0

    // per-wave constant addressing
    const int wqb2 = (cobase >> 4) * 1024 + quad * 128 + l16 * 8;  // KCH=2 base
    const int wqb4 = (cobase >> 4) * 2048 + quad * 128 + l16 * 8;  // KCH=4 base
    int aoff0[3], aoffd[3];
    mkoff(aoff0, srow, l16, quad, 0);
    int sb[3];
    #pragma unroll
    for (int nt = 0; nt < 3; ++nt) {
        const int sl = srow + nt * 16 + l16;
        sb[nt] = (sl >> 4) * 2048 + (sl & 15) * 8;
    }
    int ct[2];
    #pragma unroll
    for (int mt = 0; mt < 2; ++mt) {
        const int co4 = cobase + mt * 16 + quad * 4;
        ct[mt] = (co4 >> 5) * 512 + ((co4 >> 3) & 3) * 128 + (co4 & 7);
    }
    bool zr[3];
    #pragma unroll
    for (int nt = 0; nt < 3; ++nt) zr[nt] = zb && (srow + nt * 16 < 64);

    floatx4 acc[2][3];
    short4v x1keep[6];
    short4v dk[6];

    // ---- prologue: stage ds + c1_0k0 (both 16KB) into W0; stage X into RA
    stage_async<8192>(W0, wq + OFF_DS, wave, lane);
    stage_async<8192>(W0 + 8192, wq + OFF_L0C1_0, wave, lane);
    {
        const float* xp = x + (size_t)b * 64 * S_LEN;
        const int ci0 = wave * 4;
        const int cterm = (ci0 >> 5) * 512 + ((ci0 >> 3) & 3) * 128 + (ci0 & 7);
        #pragma unroll
        for (int h = 0; h < 3; ++h) {
            const int r = lane + h * 64;
            const int s = s0g + r;
            short4v pk;
            #pragma unroll
            for (int c4 = 0; c4 < 4; ++c4) {
                const float v = (s >= 0) ? xp[(ci0 + c4) * S_LEN + s] : 0.f;
                pk[c4] = f2bs(v);
            }
            *(short4v*)(RA + (r >> 4) * 2048 + (r & 15) * 8 + cterm) = pk;
        }
    }
    __syncthreads();                               // B0: X + W0 (ds, c1k0)

    // ---- P1: ds (1x1) -> dk regs, AND c1_0 k0 -> acc ; stage c1k1 -> W1
    stage_async<8192>(W1, wq + OFF_L0C1_1, wave, lane);
    zero_acc(acc);
    conv_tap<2>(RA, W0 + wqb2, aoff0, acc, 0);
    #pragma unroll
    for (int mt = 0; mt < 2; ++mt) {
        const int co4 = cobase + mt * 16 + quad * 4;
        const floatx4 bb = *(const floatx4*)(ds_b + co4);
        #pragma unroll
        for (int nt = 0; nt < 3; ++nt) {
            floatx4 y = acc[mt][nt] + bb;
            if (zr[nt]) y = {0.f, 0.f, 0.f, 0.f};
            dk[mt * 3 + nt] = pack4(y);
        }
    }
    mkoff(aoffd, srow, l16, quad, 1);
    zero_acc(acc);
    conv_tap<2>(RA, W0 + 8192 + wqb2, aoffd, acc, 0);
    __syncthreads();                               // B1: c1k1 weights

    // ---- P2: c1_0 k1 -> T into RB ; stage c2k0 -> W0
    stage_async<16384>(W0, wq + OFF_L0C2_0, wave, lane);
    conv_tap<2>(RA, W1 + wqb2, aoff0, acc, 0);
    #pragma unroll
    for (int mt = 0; mt < 2; ++mt) {
        const int co4 = cobase + mt * 16 + quad * 4;
        const floatx4 bb = *(const floatx4*)(b1_0 + co4);
        #pragma unroll
        for (int nt = 0; nt < 3; ++nt) {
            floatx4 y = acc[mt][nt] + bb;
            #pragma unroll
            for (int rr = 0; rr < 4; ++rr) y[rr] = elu_f(y[rr]);
            if (zr[nt]) y = {0.f, 0.f, 0.f, 0.f};
            *(short4v*)(RB + sb[nt] + ct[mt]) = pack4(y);
        }
    }
    __syncthreads();                               // B2: T + c2k0 weights

    // ---- P3: c2_0 k0 (reads RB) ; stage c2k1 -> W1
    stage_async<16384>(W1, wq + OFF_L0C2_1, wave, lane);
    zero_acc(acc);
    conv_tap<4>(RB, W0 + wqb4, aoffd, acc, 0);
    __syncthreads();                               // B3: c2k1 weights

    // ---- P4: c2_0 k1 -> x1 into RA (X dead); res = dk; keep x1
    stage_async<16384>(W0, wq + OFF_C1B, wave, lane);
    conv_tap<4>(RB, W1 + wqb4, aoff0, acc, 0);
    #pragma unroll
    for (int mt = 0; mt < 2; ++mt) {
        const int co4 = cobase + mt * 16 + quad * 4;
        const floatx4 bb = *(const floatx4*)(b2_0 + co4);
        #pragma unroll
        for (int nt = 0; nt < 3; ++nt) {
            floatx4 y = acc[mt][nt] + bb;
            const short4v d4 = dk[mt * 3 + nt];
            #pragma unroll
            for (int rr = 0; rr < 4; ++rr) {
                y[rr] = elu_f(y[rr]);
                y[rr] = elu_f(y[rr] + bs2f(d4[rr]));
            }
            if (zr[nt]) y = {0.f, 0.f, 0.f, 0.f};
            const short4v pk = pack4(y);
            *(short4v*)(RA + sb[nt] + ct[mt]) = pk;
            x1keep[mt * 3 + nt] = pk;
        }
    }
    __syncthreads();                               // B4: x1 + L1 c1k0 weights

    // ---- levels 1..3 (d = 2, 4, 8): io in RA (in-place), T in RB
    // backward row requirements (16-row granularity):
    const int mc1[3] = {0, 0, 16};   // conv1 output floor per lvl
    const int mc2[3] = {0, 16, 32};  // conv2 output floor per lvl
    #pragma unroll
    for (int lvl = 0; lvl < 3; ++lvl) {
        const int d = 2 << lvl;
        const int n1 = ntfloor(mc1[lvl], srow);
        const int n2 = ntfloor(mc2[lvl], srow);
        mkoff(aoffd, srow, l16, quad, d);
        // c1 k0 (W0), prefetch c1k1 -> W1
        stage_async<16384>(W1, wq + OFF_C1B + lvl * 32768 + 16384, wave, lane);
        zero_acc(acc);
        conv_tap<4>(RA, W0 + wqb4, aoffd, acc, n1);
        __syncthreads();
        // c1 k1 (W1) -> T into RB; prefetch c2k0 -> W0
        stage_async<16384>(W0, wq + OFF_C2B + lvl * 32768, wave, lane);
        conv_tap<4>(RA, W1 + wqb4, aoff0, acc, n1);
        #pragma unroll
        for (int mt = 0; mt < 2; ++mt) {
            const int co4 = cobase + mt * 16 + quad * 4;
            const floatx4 bb = *(const floatx4*)(B1 + lvl * 128 + co4);
            #pragma unroll
            for (int nt = 0; nt < 3; ++nt) {
                if (nt < n1) continue;
                floatx4 y = acc[mt][nt] + bb;
                #pragma unroll
                for (int rr = 0; rr < 4; ++rr) y[rr] = elu_f(y[rr]);
                if (zr[nt]) y = {0.f, 0.f, 0.f, 0.f};
                *(short4v*)(RB + sb[nt] + ct[mt]) = pack4(y);
            }
        }
        __syncthreads();
        // c2 k0 (W0), reads T(RB); prefetch c2k1 -> W1
        stage_async<16384>(W1, wq + OFF_C2B + lvl * 32768 + 16384, wave, lane);
        zero_acc(acc);
        conv_tap<4>(RB, W0 + wqb4, aoffd, acc, n2);
        __syncthreads();
        // c2 k1 (W1) -> out into RA in-place (lane-local res); prefetch next
        stage_async<16384>(W0, wq + OFF_C1B + (lvl + 1) * 32768, wave, lane);
        conv_tap<4>(RB, W1 + wqb4, aoff0, acc, n2);
        #pragma unroll
        for (int mt = 0; mt < 2; ++mt) {
            const int co4 = cobase + mt * 16 + quad * 4;
            const floatx4 bb = *(const floatx4*)(B2 + lvl * 128 + co4);
            #pragma unroll
            for (int nt = 0; nt < 3; ++nt) {
                if (nt < n2) continue;
                short* p = RA + sb[nt] + ct[mt];
                const short4v old = *(const short4v*)p;
                floatx4 y = acc[mt][nt] + bb;
                #pragma unroll
                for (int rr = 0; rr < 4; ++rr) {
                    y[rr] = elu_f(y[rr]);
                    y[rr] = elu_f(y[rr] + bs2f(old[rr]));
                }
                if (zr[nt]) y = {0.f, 0.f, 0.f, 0.f};
                *(short4v*)p = pack4(y);
            }
        }
        __syncthreads();
    }

    // ---- level 4 (d=16): c1 floor = 48 (group0 idle), c2 floor = 64
    {
        const int n1 = ntfloor(48, srow);
        const int n2 = ntfloor(64, srow);
        mkoff(aoffd, srow, l16, quad, 16);
        // c1 k0 (W0), prefetch c1k1 -> W1
        stage_async<16384>(W1, wq + OFF_C1B + 3 * 32768 + 16384, wave, lane);
        zero_acc(acc);
        conv_tap<4>(RA, W0 + wqb4, aoffd, acc, n1);
        __syncthreads();
        // c1 k1 (W1) -> T into RB; prefetch c2k0 -> W0
        stage_async<16384>(W0, wq + OFF_C2B + 3 * 32768, wave, lane);
        conv_tap<4>(RA, W1 + wqb4, aoff0, acc, n1);
        #pragma unroll
        for (int mt = 0; mt < 2; ++mt) {
            const int co4 = cobase + mt * 16 + quad * 4;
            const floatx4 bb = *(const floatx4*)(B1 + 384 + co4);
            #pragma unroll
            for (int nt = 0; nt < 3; ++nt) {
                if (nt < n1) continue;
                floatx4 y = acc[mt][nt] + bb;
                #pragma unroll
                for (int rr = 0; rr < 4; ++rr) y[rr] = elu_f(y[rr]);
                if (zr[nt]) y = {0.f, 0.f, 0.f, 0.f};
                *(short4v*)(RB + sb[nt] + ct[mt]) = pack4(y);
            }
        }
        __syncthreads();
        // c2 k0 (W0), reads T(RB); prefetch c2k1 -> W1
        stage_async<16384>(W1, wq + OFF_C2B + 3 * 32768 + 16384, wave, lane);
        zero_acc(acc);
        conv_tap<4>(RB, W0 + wqb4, aoffd, acc, n2);
        __syncthreads();
        // c2 k1 (W1) -> final epilogue, rows 64..191 only; res = RA; + x1keep
        conv_tap<4>(RB, W1 + wqb4, aoff0, acc, n2);
        #pragma unroll
        for (int mt = 0; mt < 2; ++mt) {
            const int co4 = cobase + mt * 16 + quad * 4;
            const floatx4 bb = *(const floatx4*)(B2 + 384 + co4);
            #pragma unroll
            for (int nt = 0; nt < 3; ++nt) {
                if (srow + nt * 16 < 64) continue;     // halo rows: no output
                const int sl = srow + nt * 16 + l16;
                const int sg = s0g + sl;
                const short4v res = *(const short4v*)(RA + sb[nt] + ct[mt]);
                const short4v k   = x1keep[mt * 3 + nt];
                #pragma unroll
                for (int rr = 0; rr < 4; ++rr) {
                    float y = elu_f(acc[mt][nt][rr] + bb[rr]);
                    y = elu_f(y + bs2f(res[rr]));
                    y += bs2f(k[rr]);
                    out[((size_t)(b * 128 + co4 + rr)) * S_LEN + sg] = y;
                }
            }
        }
    }
}

// ---------------------------------------------------------------------------
// weights fp32 [co][ci][k] -> bf16 tap matrices, FRAGMENT-MAJOR tiled:
// widx(co,ci) = (co>>4)*(KC*512) + (ci>>5)*512 + ((ci>>3)&3)*128 + (co&15)*8 + (ci&7)
// ---------------------------------------------------------------------------
__device__ __forceinline__ int widx(int co, int ci, int KC) {
    return (co >> 4) * (KC * 512) + (ci >> 5) * 512 + ((ci >> 3) & 3) * 128
         + (co & 15) * 8 + (ci & 7);
}

__global__ __launch_bounds__(256)
void prep_w(const float* __restrict__ w1_0, const float* __restrict__ w2_0,
            const float* __restrict__ ds_w, const float* __restrict__ W1,
            const float* __restrict__ W2, short* __restrict__ wq)
{
    int idx = blockIdx.x * 256 + threadIdx.x;
    const int n_c1 = 128 * 64;
    const int n_c2 = 128 * 128;
    if (idx < n_c1) {
        const int co = idx >> 6, ci = idx & 63;
        const int d = widx(co, ci, 2);
        wq[OFF_L0C1_0 + d] = f2bs(w1_0[idx * 2]);
        wq[OFF_L0C1_1 + d] = f2bs(w1_0[idx * 2 + 1]);
        return;
    }
    idx -= n_c1;
    if (idx < n_c2) {
        const int co = idx >> 7, ci = idx & 127;
        const int d = widx(co, ci, 4);
        wq[OFF_L0C2_0 + d] = f2bs(w2_0[idx * 2]);
        wq[OFF_L0C2_1 + d] = f2bs(w2_0[idx * 2 + 1]);
        return;
    }
    idx -= n_c2;
    if (idx < 4 * n_c2) {
        const int li = idx / n_c2, j = idx - li * n_c2;
        const int co = j >> 7, ci = j & 127;
        const int d = widx(co, ci, 4);
        wq[OFF_C1B + li * 32768 + d]         = f2bs(W1[(li * n_c2 + j) * 2]);
        wq[OFF_C1B + li * 32768 + 16384 + d] = f2bs(W1[(li * n_c2 + j) * 2 + 1]);
        return;
    }
    idx -= 4 * n_c2;
    if (idx < 4 * n_c2) {
        const int li = idx / n_c2, j = idx - li * n_c2;
        const int co = j >> 7, ci = j & 127;
        const int d = widx(co, ci, 4);
        wq[OFF_C2B + li * 32768 + d]         = f2bs(W2[(li * n_c2 + j) * 2]);
        wq[OFF_C2B + li * 32768 + 16384 + d] = f2bs(W2[(li * n_c2 + j) * 2 + 1]);
        return;
    }
    idx -= 4 * n_c2;
    if (idx < n_c1) {
        const int co = idx >> 6, ci = idx & 63;
        wq[OFF_DS + widx(co, ci, 2)] = f2bs(ds_w[idx]);
    }
}

// ---------------------------------------------------------------------------
extern "C" void kernel_launch(void* const* d_in, const int* in_sizes, int n_in,
                              void* d_out, int out_size, void* d_ws, size_t ws_size,
                              hipStream_t stream) {
    const float* x_in = (const float*)d_in[0];
    const float* w1_0 = (const float*)d_in[1];
    const float* b1_0 = (const float*)d_in[2];
    const float* w2_0 = (const float*)d_in[3];
    const float* b2_0 = (const float*)d_in[4];
    const float* ds_w = (const float*)d_in[5];
    const float* ds_b = (const float*)d_in[6];
    const float* W1   = (const float*)d_in[7];
    const float* B1   = (const float*)d_in[8];
    const float* W2   = (const float*)d_in[9];
    const float* B2   = (const float*)d_in[10];
    float* out = (float*)d_out;

    short* wq = (short*)d_ws;   // 624 KB fragment-major weight bank

    (void)hipFuncSetAttribute((const void*)tcn_fused,
                              hipFuncAttributeMaxDynamicSharedMemorySize, LDS_BYTES);

    prep_w<<<dim3(640), 256, 0, stream>>>(w1_0, w2_0, ds_w, W1, W2, wq);
    tcn_fused<<<dim3(32, 16), dim3(1024), LDS_BYTES, stream>>>(
        x_in, wq, b1_0, b2_0, ds_b, B1, B2, out);
}